// Round 5
// baseline (373.023 us; speedup 1.0000x reference)
//
#include <hip/hip_runtime.h>

typedef unsigned short ushort;
typedef unsigned int uint;
typedef __attribute__((ext_vector_type(8))) short short8;
typedef __attribute__((ext_vector_type(4))) float float4v;

#define D_MODEL 1024
#define NH 16
#define DH 64
#define BATCH 2
#define SEQ 1024
#define MEMLEN 1024
#define TOT 2048

__device__ __forceinline__ float b2f(ushort u) {
  return __uint_as_float(((uint)u) << 16);
}
__device__ __forceinline__ ushort f2b(float f) {
  uint i = __float_as_uint(f);
  uint r = (i + 0x7fffu + ((i >> 16) & 1u)) >> 16;
  return (ushort)r;
}
__device__ __forceinline__ void gld16(const ushort* g, ushort* l) {
  __builtin_amdgcn_global_load_lds(
      (const __attribute__((address_space(1))) void*)g,
      (__attribute__((address_space(3))) void*)l, 16, 0, 0);
}

// ------------------------------------------------- concat + cast to bf16 ----
__global__ __launch_bounds__(256) void concat_cvt_kernel(
    const float* __restrict__ x, const float* __restrict__ mem,
    ushort* __restrict__ xt, ushort* __restrict__ xb) {
  int idx = blockIdx.x * 256 + threadIdx.x;
  int row = idx >> 7;
  int c8 = (idx & 127) << 3;
  int b = row >> 11;
  int i = row & 2047;
  const float* src = (i < MEMLEN) ? &mem[((b << 10) + i) * D_MODEL]
                                  : &x[((b << 10) + (i - MEMLEN)) * D_MODEL];
  float4 f0 = *(const float4*)(&src[c8]);
  float4 f1 = *(const float4*)(&src[c8 + 4]);
  ushort u[8] = {f2b(f0.x), f2b(f0.y), f2b(f0.z), f2b(f0.w),
                 f2b(f1.x), f2b(f1.y), f2b(f1.z), f2b(f1.w)};
  *(uint4*)(&xt[row * D_MODEL + c8]) = *(const uint4*)u;
  if (i >= MEMLEN)
    *(uint4*)(&xb[((b << 10) + (i - MEMLEN)) * D_MODEL + c8]) = *(const uint4*)u;
}

// --------------------------------------------------- fp32 -> bf16 cast ------
__global__ __launch_bounds__(256) void cvt_kernel(const float* __restrict__ in,
                                                  ushort* __restrict__ out) {
  int idx = blockIdx.x * 256 + threadIdx.x;
  int base = idx << 3;
  float4 f0 = *(const float4*)(&in[base]);
  float4 f1 = *(const float4*)(&in[base + 4]);
  ushort u[8] = {f2b(f0.x), f2b(f0.y), f2b(f0.z), f2b(f0.w),
                 f2b(f1.x), f2b(f1.y), f2b(f1.z), f2b(f1.w)};
  *(uint4*)(&out[base]) = *(const uint4*)u;
}

// --------------------- mask -> bf16 pre-multiplied by -1e9 ------------------
__global__ __launch_bounds__(256) void maskcvt_kernel(
    const float* __restrict__ in, ushort* __restrict__ out) {
  int idx = blockIdx.x * 256 + threadIdx.x;
  int base = idx << 3;
  float4 f0 = *(const float4*)(&in[base]);
  float4 f1 = *(const float4*)(&in[base + 4]);
  ushort u[8] = {f2b(f0.x * -1e9f), f2b(f0.y * -1e9f), f2b(f0.z * -1e9f),
                 f2b(f0.w * -1e9f), f2b(f1.x * -1e9f), f2b(f1.y * -1e9f),
                 f2b(f1.z * -1e9f), f2b(f1.w * -1e9f)};
  *(uint4*)(&out[base]) = *(const uint4*)u;
}

// --------------------------- 5x transpose + cast to bf16 (one launch) -------
__global__ __launch_bounds__(256) void transpose_cvt5_kernel(
    const float* __restrict__ W0, const float* __restrict__ W1,
    const float* __restrict__ W2, const float* __restrict__ W3,
    const float* __restrict__ W4, ushort* __restrict__ T0,
    ushort* __restrict__ T1, ushort* __restrict__ T2, ushort* __restrict__ T3,
    ushort* __restrict__ T4) {
  __shared__ ushort tle[32][33];
  const float* W;
  ushort* T;
  switch (blockIdx.z) {
    case 0: W = W0; T = T0; break;
    case 1: W = W1; T = T1; break;
    case 2: W = W2; T = T2; break;
    case 3: W = W3; T = T3; break;
    default: W = W4; T = T4; break;
  }
  const int bx = blockIdx.x * 32, by = blockIdx.y * 32;
  const int tx = threadIdx.x & 31, ty = threadIdx.x >> 5;
#pragma unroll
  for (int j = 0; j < 32; j += 8)
    tle[ty + j][tx] = f2b(W[(by + ty + j) * 1024 + bx + tx]);
  __syncthreads();
#pragma unroll
  for (int j = 0; j < 32; j += 8)
    T[(bx + ty + j) * 1024 + by + tx] = tle[tx][ty + j];
}

// ------------------------------------- V transpose: kv cols -> vt[b][d][t] --
__global__ __launch_bounds__(256) void vtrans_kernel(
    const ushort* __restrict__ kv, ushort* __restrict__ vt) {
  __shared__ ushort tle[32][76];
  const int gx = blockIdx.x;   // 32-row (b,t) tiles
  const int gy = blockIdx.y;   // 64-wide d tiles
  const int tid = threadIdx.x;
  const int r = tid >> 3, c8 = (tid & 7) * 8;
  *(uint4*)(&tle[r][c8]) =
      *(const uint4*)(&kv[(gx * 32 + r) * 2048 + 1024 + gy * 64 + c8]);
  __syncthreads();
  const int dr = tid >> 2, tc8 = (tid & 3) * 8;
  const int bb = (gx * 32) >> 11, tbase = (gx * 32) & 2047;
  ushort tmp[8];
#pragma unroll
  for (int j = 0; j < 8; ++j) tmp[j] = tle[tc8 + j][dr];
  *(uint4*)(&vt[((bb << 10) + gy * 64 + dr) * 2048 + tbase + tc8]) =
      *(const uint4*)tmp;
}

// --------------- fused projection GEMM: KV + q + qrel in one launch ---------
// 768 blocks of 128x128 tiles, K=1024, m97-style global_load_lds staging.
// seg0 (bid<512): kv = xt @ [WkeT;WvT], col-based bias/scale (K cols *0.125).
// seg1 (bid>=512): qr = xbrel @ (WqT | WkrT by row), row-based bias/scale
//                  (qrel rows pre-scaled 0.125).
__global__ __launch_bounds__(256) void gemm_fused_kernel(
    const ushort* __restrict__ xt, const ushort* __restrict__ xbrel,
    const ushort* __restrict__ WkeT, const ushort* __restrict__ WqT,
    const ushort* __restrict__ WkrT, const float* __restrict__ bke,
    const float* __restrict__ bv, const float* __restrict__ bq,
    const float* __restrict__ bkr, ushort* __restrict__ kv,
    ushort* __restrict__ qr) {
  __shared__ ushort As[128 * 32];
  __shared__ ushort Bs[128 * 32];
  const int bid = blockIdx.x;
  const bool seg0 = (bid < 512);
  const ushort* A;
  const ushort* BT;
  ushort* C;
  int ldC, m0, n0;
  if (seg0) {
    m0 = (bid & 31) * 128;
    n0 = (bid >> 5) * 128;
    A = xt;
    BT = WkeT;   // rows >=1024 fall through into adjacent WvT
    C = kv;
    ldC = 2048;
  } else {
    int g = bid - 512;
    m0 = (g & 31) * 128;
    n0 = (g >> 5) * 128;
    A = xbrel;
    BT = (m0 < 2048) ? WqT : WkrT;
    C = qr;
    ldC = 1024;
  }
  const int tid = threadIdx.x;
  const int w = tid >> 6, lane = tid & 63, m15 = lane & 15, q4 = lane >> 4;
  const int wm = w & 1, wn = w >> 1;
  float4v acc[4][4] = {};
  const int c0 = tid, c1 = tid + 256;
  const int r0 = c0 >> 2, u0 = (c0 & 3) * 8;
  const int r1 = c1 >> 2, u1 = (c1 & 3) * 8;

  for (int kk = 0; kk < 1024; kk += 32) {
    __syncthreads();
    gld16(&A[(m0 + r0) * 1024 + kk + u0], &As[c0 * 8]);
    gld16(&A[(m0 + r1) * 1024 + kk + u1], &As[c1 * 8]);
    gld16(&BT[(n0 + r0) * 1024 + kk + u0], &Bs[c0 * 8]);
    gld16(&BT[(n0 + r1) * 1024 + kk + u1], &Bs[c1 * 8]);
    __syncthreads();
    short8 af[4], bf[4];
#pragma unroll
    for (int i = 0; i < 4; ++i)
      af[i] = *(const short8*)(&As[(wm * 64 + i * 16 + m15) * 32 + q4 * 8]);
#pragma unroll
    for (int j = 0; j < 4; ++j)
      bf[j] = *(const short8*)(&Bs[(wn * 64 + j * 16 + m15) * 32 + q4 * 8]);
#pragma unroll
    for (int i = 0; i < 4; ++i)
#pragma unroll
      for (int j = 0; j < 4; ++j)
        acc[i][j] =
            __builtin_amdgcn_mfma_f32_16x16x32_bf16(af[i], bf[j], acc[i][j], 0, 0, 0);
  }
#pragma unroll
  for (int j = 0; j < 4; ++j) {
    int col = n0 + wn * 64 + j * 16 + m15;
    float bb, sc;
    if (seg0) {
      bb = (col < 1024) ? bke[col] : bv[col - 1024];
      sc = (col < 1024) ? 0.125f : 1.0f;
    } else {
      bb = (m0 < 2048) ? bq[col] : bkr[col];
      sc = (m0 < 2048) ? 1.0f : 0.125f;
    }
#pragma unroll
    for (int i = 0; i < 4; ++i) {
      int rowb = m0 + wm * 64 + i * 16 + q4 * 4;
#pragma unroll
      for (int r = 0; r < 4; ++r)
        C[(rowb + r) * ldC + col] = f2b((acc[i][j][r] + bb) * sc);
    }
  }
}

// -------------------------------------- 64x128-tile GEMM (output proj) ------
template <int EPI>
__global__ __launch_bounds__(256) void gemm64_kernel(
    const ushort* __restrict__ A, const ushort* __restrict__ BT,
    const float* __restrict__ bias, void* __restrict__ Cout, int M, int N,
    int K) {
  __shared__ ushort As[64 * 32];
  __shared__ ushort Bs[128 * 32];
  const int m0 = blockIdx.x * 64, n0 = blockIdx.y * 128;
  const int tid = threadIdx.x;
  const int w = tid >> 6, lane = tid & 63, m15 = lane & 15, q4 = lane >> 4;
  float4v acc[4][2] = {};
  const int ra = tid >> 2, ua = (tid & 3) * 8;
  const int c0 = tid, c1 = tid + 256;
  const int rb0 = c0 >> 2, ub0 = (c0 & 3) * 8;
  const int rb1 = c1 >> 2, ub1 = (c1 & 3) * 8;

  for (int kk = 0; kk < K; kk += 32) {
    __syncthreads();
    gld16(&A[(m0 + ra) * K + kk + ua], &As[tid * 8]);
    gld16(&BT[(n0 + rb0) * K + kk + ub0], &Bs[c0 * 8]);
    gld16(&BT[(n0 + rb1) * K + kk + ub1], &Bs[c1 * 8]);
    __syncthreads();
    short8 bf[2];
#pragma unroll
    for (int j = 0; j < 2; ++j)
      bf[j] = *(const short8*)(&Bs[(w * 32 + j * 16 + m15) * 32 + q4 * 8]);
#pragma unroll
    for (int i = 0; i < 4; ++i) {
      short8 af = *(const short8*)(&As[(i * 16 + m15) * 32 + q4 * 8]);
#pragma unroll
      for (int j = 0; j < 2; ++j)
        acc[i][j] =
            __builtin_amdgcn_mfma_f32_16x16x32_bf16(af, bf[j], acc[i][j], 0, 0, 0);
    }
  }
#pragma unroll
  for (int j = 0; j < 2; ++j) {
    int col = n0 + w * 32 + j * 16 + m15;
    float bv = bias[col];
#pragma unroll
    for (int i = 0; i < 4; ++i) {
      int rowb = m0 + i * 16 + q4 * 4;
#pragma unroll
      for (int r = 0; r < 4; ++r) {
        float v = acc[i][j][r] + bv;
        if (EPI == 1)
          ((float*)Cout)[(rowb + r) * N + col] = v;
        else
          ((ushort*)Cout)[(rowb + r) * N + col] = f2b(v);
      }
    }
  }
}

// ----------------------- Bhat batched GEMM + mask fold ----------------------
// Bh[b,h,sp,u] = q[sp].Qrel[u] (Qrel pre-scaled 1/8) + mask for the (s,t)
// cell that will READ this element in attn. Band-A reads (u >= 1023-sp,
// consumer (sp, t=u+sp-1023)) and wrap reads (u < 1023-sp, consumer
// (sp-1, t=u+sp+1025)) are provably disjoint, so exactly one mask value is
// correct per cell. Mask reads are row-contiguous (L2-hot, 4 MB).
__global__ __launch_bounds__(256) void bhat_kernel(
    const ushort* __restrict__ q, const ushort* __restrict__ Qrb,
    const ushort* __restrict__ maskb, ushort* __restrict__ Bh) {
  __shared__ ushort As[2 * 128 * 32];
  __shared__ ushort Bs[2 * 128 * 32];
  const int bs0 = blockIdx.x * 128, u0 = blockIdx.y * 128, h = blockIdx.z;
  const int tid = threadIdx.x;
  const int w = tid >> 6, lane = tid & 63, m15 = lane & 15, q4 = lane >> 4;
  const int wm = w & 1, wn = w >> 1;

#pragma unroll
  for (int c = 0; c < 4; ++c) {
    int unit = c * 256 + tid;               // flat LDS ushort = unit*8
    int row = (unit >> 2) & 127, kh = unit >> 9, cu = unit & 3;
    gld16(&q[(bs0 + row) * 1024 + (h << 6) + kh * 32 + cu * 8], &As[unit * 8]);
    gld16(&Qrb[(u0 + row) * 1024 + (h << 6) + kh * 32 + cu * 8], &Bs[unit * 8]);
  }
  __syncthreads();

  float4v acc[4][4] = {};
#pragma unroll
  for (int kh = 0; kh < 2; ++kh) {
    short8 af[4], bf[4];
#pragma unroll
    for (int i = 0; i < 4; ++i)
      af[i] = *(const short8*)(&As[kh * 4096 + (wm * 64 + i * 16 + m15) * 32 + q4 * 8]);
#pragma unroll
    for (int j = 0; j < 4; ++j)
      bf[j] = *(const short8*)(&Bs[kh * 4096 + (wn * 64 + j * 16 + m15) * 32 + q4 * 8]);
#pragma unroll
    for (int i = 0; i < 4; ++i)
#pragma unroll
      for (int j = 0; j < 4; ++j)
        acc[i][j] =
            __builtin_amdgcn_mfma_f32_16x16x32_bf16(af[i], bf[j], acc[i][j], 0, 0, 0);
  }
  const int b = bs0 >> 10;
  const int s0loc = bs0 & 1023;
  const int outrow0 = ((b << 4) + h) * 1024 + s0loc;
#pragma unroll
  for (int j = 0; j < 4; ++j) {
    int u = u0 + wn * 64 + j * 16 + m15;
#pragma unroll
    for (int i = 0; i < 4; ++i) {
      int rowb = outrow0 + wm * 64 + i * 16 + q4 * 4;
      int spb = s0loc + wm * 64 + i * 16 + q4 * 4;
#pragma unroll
      for (int r = 0; r < 4; ++r) {
        int sp = spb + r;
        bool selA = (u >= 1023 - sp);
        int mrow = selA ? sp : (sp > 0 ? sp - 1 : 0);
        int mcol = selA ? (u + sp - 1023) : (u + sp + 1025);
        float mval = b2f(maskb[mrow * 2048 + mcol]);
        Bh[(rowb + r) * 2048 + u] = f2b(acc[i][j][r] + mval);
      }
    }
  }
}

// ----------------- fused attention: QK + deep B-gather + exp + PV -----------
// Wave-independent: block = one 16-row s-tile; wave w = T-QUARTER (512 t,
// 16 chunks of 32). 2048 blocks -> ~2.5x the resident waves of the old
// half-split (latency hiding). ZERO barriers in the loop; B-hat gathered
// with 4 rotating register buffers; mask pre-folded into Bh by producer;
// u==2048 zero-diagonal mask preloaded per wave (dm). 4-way partial combine
// at the end via LDS.
__global__ __launch_bounds__(256) void attn_kernel(
    const ushort* __restrict__ qb, const ushort* __restrict__ kv,
    const ushort* __restrict__ vt, const ushort* __restrict__ Bh,
    const ushort* __restrict__ maskb, ushort* __restrict__ attn) {
  __shared__ ushort Pp[4][16 * 36];
  __shared__ float comb[3][16][68];
  __shared__ float csum[3][16];

  const int tid = threadIdx.x;
  const int w = tid >> 6, lane = tid & 63, m15 = lane & 15, q4 = lane >> 4;
  const int th = w;                       // T-quarter
  const int s0w = blockIdx.x * 16;
  const int h = blockIdx.y, b = blockIdx.z;
  const int s_l = q4 * 4;

  const ushort* qp = &qb[((b << 10) + s0w + m15) * 1024 + (h << 6) + q4 * 8];
  const short8 af0 = *(const short8*)qp;
  const short8 af1 = *(const short8*)(qp + 32);

  const ushort* kvb = &kv[((size_t)(b << 11) * 2048) + (h << 6)];
  const ushort* vtb = &vt[((size_t)((b << 10) + (h << 6))) * 2048];
  const int bhbase = ((b << 4) + h) << 21;   // *(1024*2048)
  ushort* pw = &Pp[w][0];

  int offA[4], offB[4], diagT[4];
  float dm[4];
#pragma unroll
  for (int i = 0; i < 4; ++i) {
    int s = s0w + s_l + i;
    offA[i] = bhbase + (s << 11) - s + 1023;
    offB[i] = bhbase + ((s + 1) << 11) - s - 1026;
    diagT[i] = s + 1025;
    dm[i] = (diagT[i] <= 2047) ? b2f(maskb[s * 2048 + diagT[i]]) : 0.f;
  }

  float lsum4[4] = {0.f, 0.f, 0.f, 0.f};
  float4v oacc[4] = {};
  ushort Bb0[8], Bb1[8], Bb2[8], Bb3[8];

  auto pre_bh = [&](int t0, ushort (&B)[8]) {
#pragma unroll
    for (int nt = 0; nt < 2; ++nt)
#pragma unroll
      for (int i = 0; i < 4; ++i) {
        int t = t0 + nt * 16 + m15;
        int off = (t < diagT[i]) ? offA[i] : offB[i];   // t <= s+1024 -> A
        B[nt * 4 + i] = Bh[off + t];
      }
  };

  auto phase = [&](int t0, ushort (&Bb)[8], bool pf) {
    short8 Vr[4], Kr[2][2];
#pragma unroll
    for (int nd = 0; nd < 4; ++nd)
      Vr[nd] = *(const short8*)(&vtb[(size_t)(nd * 16 + m15) * 2048 + t0 + q4 * 8]);
#pragma unroll
    for (int nt = 0; nt < 2; ++nt) {
      const ushort* kp = &kvb[(size_t)(t0 + nt * 16 + m15) * 2048 + q4 * 8];
      Kr[nt][0] = *(const short8*)kp;
      Kr[nt][1] = *(const short8*)(kp + 32);
    }
    ushort cur[8];
#pragma unroll
    for (int j = 0; j < 8; ++j) cur[j] = Bb[j];
    if (pf) pre_bh(t0 + 128, Bb);
    float4v a0 = {}, a1 = {};
    a0 = __builtin_amdgcn_mfma_f32_16x16x32_bf16(af0, Kr[0][0], a0, 0, 0, 0);
    a0 = __builtin_amdgcn_mfma_f32_16x16x32_bf16(af1, Kr[0][1], a0, 0, 0, 0);
    a1 = __builtin_amdgcn_mfma_f32_16x16x32_bf16(af0, Kr[1][0], a1, 0, 0, 0);
    a1 = __builtin_amdgcn_mfma_f32_16x16x32_bf16(af1, Kr[1][1], a1, 0, 0, 0);
#pragma unroll
    for (int nt = 0; nt < 2; ++nt)
#pragma unroll
      for (int i = 0; i < 4; ++i) {
        int t = t0 + nt * 16 + m15;
        float bv = (t == diagT[i]) ? dm[i] : b2f(cur[nt * 4 + i]);
        float a = (nt == 0) ? a0[i] : a1[i];
        float p = __expf(a + bv);
        lsum4[i] += p;
        pw[(s_l + i) * 36 + nt * 16 + m15] = f2b(p);
      }
    short8 pfr = *(const short8*)(&pw[m15 * 36 + q4 * 8]);
#pragma unroll
    for (int nd = 0; nd < 4; ++nd)
      oacc[nd] =
          __builtin_amdgcn_mfma_f32_16x16x32_bf16(pfr, Vr[nd], oacc[nd], 0, 0, 0);
  };

  const int tb = th * 512;
  pre_bh(tb, Bb0);
  pre_bh(tb + 32, Bb1);
  pre_bh(tb + 64, Bb2);
  pre_bh(tb + 96, Bb3);
  for (int it = 0; it < 4; ++it) {
    const int t0 = tb + it * 128;
    const bool pf = (it < 3);
    phase(t0, Bb0, pf);
    phase(t0 + 32, Bb1, pf);
    phase(t0 + 64, Bb2, pf);
    phase(t0 + 96, Bb3, pf);
  }

  // row sums across the 16 t-lanes (m15 butterfly)
#pragma unroll
  for (int i = 0; i < 4; ++i) {
    float v = lsum4[i];
    v += __shfl_xor(v, 1, 64);
    v += __shfl_xor(v, 2, 64);
    v += __shfl_xor(v, 4, 64);
    v += __shfl_xor(v, 8, 64);
    lsum4[i] = v;
  }
  // combine the 4 T-quarters
  if (th > 0) {
#pragma unroll
    for (int nd = 0; nd < 4; ++nd)
#pragma unroll
      for (int i = 0; i < 4; ++i)
        comb[th - 1][s_l + i][nd * 16 + m15] = oacc[nd][i];
    if (m15 == 0)
#pragma unroll
      for (int i = 0; i < 4; ++i) csum[th - 1][s_l + i] = lsum4[i];
  }
  __syncthreads();
  if (th == 0) {
#pragma unroll
    for (int i = 0; i < 4; ++i)
      lsum4[i] += csum[0][s_l + i] + csum[1][s_l + i] + csum[2][s_l + i];
#pragma unroll
    for (int nd = 0; nd < 4; ++nd)
#pragma unroll
      for (int i = 0; i < 4; ++i) {
        float v = oacc[nd][i] + comb[0][s_l + i][nd * 16 + m15] +
                  comb[1][s_l + i][nd * 16 + m15] +
                  comb[2][s_l + i][nd * 16 + m15];
        attn[((b << 10) + s0w + s_l + i) * 1024 + (h << 6) + nd * 16 + m15] =
            f2b(v / lsum4[i]);
      }
  }
}

// ---------------------------------------------------------------- launch ----
extern "C" void kernel_launch(void* const* d_in, const int* in_sizes, int n_in,
                              void* d_out, int out_size, void* d_ws,
                              size_t ws_size, hipStream_t stream) {
  const float* x = (const float*)d_in[0];
  const float* mem = (const float*)d_in[1];
  const float* mask = (const float*)d_in[2];
  const float* rel = (const float*)d_in[3];
  const float* Wq = (const float*)d_in[4];
  const float* bq = (const float*)d_in[5];
  const float* Wke = (const float*)d_in[6];
  const float* bke = (const float*)d_in[7];
  const float* Wkr = (const float*)d_in[8];
  const float* bkr = (const float*)d_in[9];
  const float* Wv = (const float*)d_in[10];
  const float* bv = (const float*)d_in[11];
  const float* Wo = (const float*)d_in[12];
  const float* bo = (const float*)d_in[13];
  float* out = (float*)d_out;

  ushort* ws = (ushort*)d_ws;
  ushort* xt = ws;                          // 4096x1024 (reused as vt)
  ushort* xbrel = xt + 4096 * 1024;         // [xb(2048); relb(2048)] x 1024
  ushort* WqT = xbrel + 4096 * 1024;
  ushort* WkeT = WqT + 1024 * 1024;
  ushort* WvT = WkeT + 1024 * 1024;         // must stay adjacent to WkeT
  ushort* WkrT = WvT + 1024 * 1024;
  ushort* WoT = WkrT + 1024 * 1024;
  ushort* kv = WoT + 1024 * 1024;           // 4096x2048 (K cols scaled, V)
  ushort* qr = kv + 4096 * 2048;            // [qbuf(2048); Qrb(2048)] x 1024
  ushort* attn = qr + 4096 * 1024;          // 2048x1024
  ushort* maskb = attn + 2048 * 1024;       // 1024x2048 bf16 pre-scaled
  ushort* Bh = maskb + 1024 * 2048;         // [b*16+h][1024 s][2048 u] bf16
  ushort* relb = xbrel + 2048 * 1024;
  ushort* Qrb = qr + 2048 * 1024;           // Qrel, pre-scaled by 1/8
  ushort* vt = xt;

  concat_cvt_kernel<<<2048, 256, 0, stream>>>(x, mem, xt, xbrel);
  cvt_kernel<<<1024, 256, 0, stream>>>(rel, relb);
  maskcvt_kernel<<<1024, 256, 0, stream>>>(mask, maskb);
  transpose_cvt5_kernel<<<dim3(32, 32, 5), 256, 0, stream>>>(
      Wq, Wke, Wkr, Wv, Wo, WqT, WkeT, WkrT, WvT, WoT);

  gemm_fused_kernel<<<768, 256, 0, stream>>>(xt, xbrel, WkeT, WqT, WkrT, bke,
                                             bv, bq, bkr, kv, qr);
  vtrans_kernel<<<dim3(128, 16), 256, 0, stream>>>(kv, vt);

  bhat_kernel<<<dim3(16, 16, 16), 256, 0, stream>>>(qr, Qrb, maskb, Bh);

  attn_kernel<<<dim3(SEQ / 16, NH, BATCH), 256, 0, stream>>>(
      qr, kv, vt, Bh, maskb, attn);

  gemm64_kernel<1><<<dim3(32, 8), 256, 0, stream>>>(attn, WoT, bo, out, 2048,
                                                    1024, 1024);
}

// Round 6
// 372.422 us; speedup vs baseline: 1.0016x; 1.0016x over previous
//
#include <hip/hip_runtime.h>

typedef unsigned short ushort;
typedef unsigned int uint;
typedef __attribute__((ext_vector_type(8))) short short8;
typedef __attribute__((ext_vector_type(4))) float float4v;

#define D_MODEL 1024
#define NH 16
#define DH 64
#define BATCH 2
#define SEQ 1024
#define MEMLEN 1024
#define TOT 2048

__device__ __forceinline__ float b2f(ushort u) {
  return __uint_as_float(((uint)u) << 16);
}
__device__ __forceinline__ ushort f2b(float f) {
  uint i = __float_as_uint(f);
  uint r = (i + 0x7fffu + ((i >> 16) & 1u)) >> 16;
  return (ushort)r;
}
__device__ __forceinline__ void gld16(const ushort* g, ushort* l) {
  __builtin_amdgcn_global_load_lds(
      (const __attribute__((address_space(1))) void*)g,
      (__attribute__((address_space(3))) void*)l, 16, 0, 0);
}

// ---------------- fused preprocessing: concat+cast, rel cast, mask cast -----
__global__ __launch_bounds__(256) void preproc_kernel(
    const float* __restrict__ x, const float* __restrict__ mem,
    const float* __restrict__ rel, const float* __restrict__ mask,
    ushort* __restrict__ xt, ushort* __restrict__ xb,
    ushort* __restrict__ relb, ushort* __restrict__ maskb) {
  const int bid = blockIdx.x;
  if (bid < 2048) {
    int idx = bid * 256 + threadIdx.x;
    int row = idx >> 7;
    int c8 = (idx & 127) << 3;
    int b = row >> 11;
    int i = row & 2047;
    const float* src = (i < MEMLEN) ? &mem[((b << 10) + i) * D_MODEL]
                                    : &x[((b << 10) + (i - MEMLEN)) * D_MODEL];
    float4 f0 = *(const float4*)(&src[c8]);
    float4 f1 = *(const float4*)(&src[c8 + 4]);
    ushort u[8] = {f2b(f0.x), f2b(f0.y), f2b(f0.z), f2b(f0.w),
                   f2b(f1.x), f2b(f1.y), f2b(f1.z), f2b(f1.w)};
    *(uint4*)(&xt[row * D_MODEL + c8]) = *(const uint4*)u;
    if (i >= MEMLEN)
      *(uint4*)(&xb[((b << 10) + (i - MEMLEN)) * D_MODEL + c8]) =
          *(const uint4*)u;
  } else if (bid < 3072) {
    int idx = (bid - 2048) * 256 + threadIdx.x;
    int base = idx << 3;
    float4 f0 = *(const float4*)(&rel[base]);
    float4 f1 = *(const float4*)(&rel[base + 4]);
    ushort u[8] = {f2b(f0.x), f2b(f0.y), f2b(f0.z), f2b(f0.w),
                   f2b(f1.x), f2b(f1.y), f2b(f1.z), f2b(f1.w)};
    *(uint4*)(&relb[base]) = *(const uint4*)u;
  } else {
    int idx = (bid - 3072) * 256 + threadIdx.x;
    int base = idx << 3;
    float4 f0 = *(const float4*)(&mask[base]);
    float4 f1 = *(const float4*)(&mask[base + 4]);
    ushort u[8] = {f2b(f0.x * -1e9f), f2b(f0.y * -1e9f), f2b(f0.z * -1e9f),
                   f2b(f0.w * -1e9f), f2b(f1.x * -1e9f), f2b(f1.y * -1e9f),
                   f2b(f1.z * -1e9f), f2b(f1.w * -1e9f)};
    *(uint4*)(&maskb[base]) = *(const uint4*)u;
  }
}

// --------------------------- 5x transpose + cast to bf16 (one launch) -------
__global__ __launch_bounds__(256) void transpose_cvt5_kernel(
    const float* __restrict__ W0, const float* __restrict__ W1,
    const float* __restrict__ W2, const float* __restrict__ W3,
    const float* __restrict__ W4, ushort* __restrict__ T0,
    ushort* __restrict__ T1, ushort* __restrict__ T2, ushort* __restrict__ T3,
    ushort* __restrict__ T4) {
  __shared__ ushort tle[32][33];
  const float* W;
  ushort* T;
  switch (blockIdx.z) {
    case 0: W = W0; T = T0; break;
    case 1: W = W1; T = T1; break;
    case 2: W = W2; T = T2; break;
    case 3: W = W3; T = T3; break;
    default: W = W4; T = T4; break;
  }
  const int bx = blockIdx.x * 32, by = blockIdx.y * 32;
  const int tx = threadIdx.x & 31, ty = threadIdx.x >> 5;
#pragma unroll
  for (int j = 0; j < 32; j += 8)
    tle[ty + j][tx] = f2b(W[(by + ty + j) * 1024 + bx + tx]);
  __syncthreads();
#pragma unroll
  for (int j = 0; j < 32; j += 8)
    T[(bx + ty + j) * 1024 + by + tx] = tle[tx][ty + j];
}

// --------------- fused projection GEMM: KV + q + qrel in one launch ---------
// seg0 (bid<512): K cols -> kv (scaled 0.125, bke); V cols -> written DIRECTLY
//   TRANSPOSED into kv's unused V-half region via split-row mapping:
//   V[d_g][t] lives at kv[(d_g*2 + (t>>10))*2048 + 1024 + (t&1023)].
// seg1 (bid>=512): qr = xbrel @ (WqT | WkrT by row); qrel rows scaled 0.125.
__global__ __launch_bounds__(256) void gemm_fused_kernel(
    const ushort* __restrict__ xt, const ushort* __restrict__ xbrel,
    const ushort* __restrict__ WkeT, const ushort* __restrict__ WqT,
    const ushort* __restrict__ WkrT, const float* __restrict__ bke,
    const float* __restrict__ bv, const float* __restrict__ bq,
    const float* __restrict__ bkr, ushort* __restrict__ kv,
    ushort* __restrict__ qr) {
  __shared__ ushort As[128 * 32];
  __shared__ ushort Bs[128 * 32];
  const int bid = blockIdx.x;
  const bool seg0 = (bid < 512);
  const ushort* A;
  const ushort* BT;
  int m0, n0;
  if (seg0) {
    m0 = (bid & 31) * 128;
    n0 = (bid >> 5) * 128;
    A = xt;
    BT = WkeT;   // rows >=1024 fall through into adjacent WvT
  } else {
    int g = bid - 512;
    m0 = (g & 31) * 128;
    n0 = (g >> 5) * 128;
    A = xbrel;
    BT = (m0 < 2048) ? WqT : WkrT;
  }
  const int tid = threadIdx.x;
  const int w = tid >> 6, lane = tid & 63, m15 = lane & 15, q4 = lane >> 4;
  const int wm = w & 1, wn = w >> 1;
  float4v acc[4][4] = {};
  const int c0 = tid, c1 = tid + 256;
  const int r0 = c0 >> 2, u0 = (c0 & 3) * 8;
  const int r1 = c1 >> 2, u1 = (c1 & 3) * 8;

  for (int kk = 0; kk < 1024; kk += 32) {
    __syncthreads();
    gld16(&A[(m0 + r0) * 1024 + kk + u0], &As[c0 * 8]);
    gld16(&A[(m0 + r1) * 1024 + kk + u1], &As[c1 * 8]);
    gld16(&BT[(n0 + r0) * 1024 + kk + u0], &Bs[c0 * 8]);
    gld16(&BT[(n0 + r1) * 1024 + kk + u1], &Bs[c1 * 8]);
    __syncthreads();
    short8 af[4], bf[4];
#pragma unroll
    for (int i = 0; i < 4; ++i)
      af[i] = *(const short8*)(&As[(wm * 64 + i * 16 + m15) * 32 + q4 * 8]);
#pragma unroll
    for (int j = 0; j < 4; ++j)
      bf[j] = *(const short8*)(&Bs[(wn * 64 + j * 16 + m15) * 32 + q4 * 8]);
#pragma unroll
    for (int i = 0; i < 4; ++i)
#pragma unroll
      for (int j = 0; j < 4; ++j)
        acc[i][j] =
            __builtin_amdgcn_mfma_f32_16x16x32_bf16(af[i], bf[j], acc[i][j], 0, 0, 0);
  }
#pragma unroll
  for (int j = 0; j < 4; ++j) {
    int col = n0 + wn * 64 + j * 16 + m15;
    if (seg0) {
      if (col < 1024) {
        float bb = bke[col];
#pragma unroll
        for (int i = 0; i < 4; ++i) {
          int rowb = m0 + wm * 64 + i * 16 + q4 * 4;
#pragma unroll
          for (int r = 0; r < 4; ++r)
            kv[(rowb + r) * 2048 + col] = f2b((acc[i][j][r] + bb) * 0.125f);
        }
      } else {
        float bb = bv[col - 1024];
#pragma unroll
        for (int i = 0; i < 4; ++i) {
          int rowb = m0 + wm * 64 + i * 16 + q4 * 4;
          int dg = ((rowb >> 11) << 10) + (col - 1024);
          size_t prow = (size_t)(dg * 2 + ((rowb >> 10) & 1)) * 2048 + 1024 +
                        (rowb & 1023);
          uint lo = (uint)f2b(acc[i][j][0] + bb) |
                    ((uint)f2b(acc[i][j][1] + bb) << 16);
          uint hi = (uint)f2b(acc[i][j][2] + bb) |
                    ((uint)f2b(acc[i][j][3] + bb) << 16);
          *(uint2*)(&kv[prow]) = make_uint2(lo, hi);
        }
      }
    } else {
      float bb = (m0 < 2048) ? bq[col] : bkr[col];
      float sc = (m0 < 2048) ? 1.0f : 0.125f;
#pragma unroll
      for (int i = 0; i < 4; ++i) {
        int rowb = m0 + wm * 64 + i * 16 + q4 * 4;
#pragma unroll
        for (int r = 0; r < 4; ++r)
          qr[(rowb + r) * 1024 + col] = f2b((acc[i][j][r] + bb) * sc);
      }
    }
  }
}

// -------------------------------------- 64x128-tile GEMM (output proj) ------
template <int EPI>
__global__ __launch_bounds__(256) void gemm64_kernel(
    const ushort* __restrict__ A, const ushort* __restrict__ BT,
    const float* __restrict__ bias, void* __restrict__ Cout, int M, int N,
    int K) {
  __shared__ ushort As[64 * 32];
  __shared__ ushort Bs[128 * 32];
  const int m0 = blockIdx.x * 64, n0 = blockIdx.y * 128;
  const int tid = threadIdx.x;
  const int w = tid >> 6, lane = tid & 63, m15 = lane & 15, q4 = lane >> 4;
  float4v acc[4][2] = {};
  const int ra = tid >> 2, ua = (tid & 3) * 8;
  const int c0 = tid, c1 = tid + 256;
  const int rb0 = c0 >> 2, ub0 = (c0 & 3) * 8;
  const int rb1 = c1 >> 2, ub1 = (c1 & 3) * 8;

  for (int kk = 0; kk < K; kk += 32) {
    __syncthreads();
    gld16(&A[(m0 + ra) * K + kk + ua], &As[tid * 8]);
    gld16(&BT[(n0 + rb0) * K + kk + ub0], &Bs[c0 * 8]);
    gld16(&BT[(n0 + rb1) * K + kk + ub1], &Bs[c1 * 8]);
    __syncthreads();
    short8 bf[2];
#pragma unroll
    for (int j = 0; j < 2; ++j)
      bf[j] = *(const short8*)(&Bs[(w * 32 + j * 16 + m15) * 32 + q4 * 8]);
#pragma unroll
    for (int i = 0; i < 4; ++i) {
      short8 af = *(const short8*)(&As[(i * 16 + m15) * 32 + q4 * 8]);
#pragma unroll
      for (int j = 0; j < 2; ++j)
        acc[i][j] =
            __builtin_amdgcn_mfma_f32_16x16x32_bf16(af, bf[j], acc[i][j], 0, 0, 0);
    }
  }
#pragma unroll
  for (int j = 0; j < 2; ++j) {
    int col = n0 + w * 32 + j * 16 + m15;
    float bv = bias[col];
#pragma unroll
    for (int i = 0; i < 4; ++i) {
      int rowb = m0 + i * 16 + q4 * 4;
#pragma unroll
      for (int r = 0; r < 4; ++r) {
        float v = acc[i][j][r] + bv;
        if (EPI == 1)
          ((float*)Cout)[(rowb + r) * N + col] = v;
        else
          ((ushort*)Cout)[(rowb + r) * N + col] = f2b(v);
      }
    }
  }
}

// ----------------------- Bhat batched GEMM + mask fold ----------------------
// Bh[b,h,sp,u] = q[sp].Qrel[u] (Qrel pre-scaled 1/8) + mask for the (s,t)
// cell that will READ this element in attn (band-A and wrap reads disjoint).
__global__ __launch_bounds__(256) void bhat_kernel(
    const ushort* __restrict__ q, const ushort* __restrict__ Qrb,
    const ushort* __restrict__ maskb, ushort* __restrict__ Bh) {
  __shared__ ushort As[2 * 128 * 32];
  __shared__ ushort Bs[2 * 128 * 32];
  const int bs0 = blockIdx.x * 128, u0 = blockIdx.y * 128, h = blockIdx.z;
  const int tid = threadIdx.x;
  const int w = tid >> 6, lane = tid & 63, m15 = lane & 15, q4 = lane >> 4;
  const int wm = w & 1, wn = w >> 1;

#pragma unroll
  for (int c = 0; c < 4; ++c) {
    int unit = c * 256 + tid;               // flat LDS ushort = unit*8
    int row = (unit >> 2) & 127, kh = unit >> 9, cu = unit & 3;
    gld16(&q[(bs0 + row) * 1024 + (h << 6) + kh * 32 + cu * 8], &As[unit * 8]);
    gld16(&Qrb[(u0 + row) * 1024 + (h << 6) + kh * 32 + cu * 8], &Bs[unit * 8]);
  }
  __syncthreads();

  float4v acc[4][4] = {};
#pragma unroll
  for (int kh = 0; kh < 2; ++kh) {
    short8 af[4], bf[4];
#pragma unroll
    for (int i = 0; i < 4; ++i)
      af[i] = *(const short8*)(&As[kh * 4096 + (wm * 64 + i * 16 + m15) * 32 + q4 * 8]);
#pragma unroll
    for (int j = 0; j < 4; ++j)
      bf[j] = *(const short8*)(&Bs[kh * 4096 + (wn * 64 + j * 16 + m15) * 32 + q4 * 8]);
#pragma unroll
    for (int i = 0; i < 4; ++i)
#pragma unroll
      for (int j = 0; j < 4; ++j)
        acc[i][j] =
            __builtin_amdgcn_mfma_f32_16x16x32_bf16(af[i], bf[j], acc[i][j], 0, 0, 0);
  }
  const int b = bs0 >> 10;
  const int s0loc = bs0 & 1023;
  const int outrow0 = ((b << 4) + h) * 1024 + s0loc;
#pragma unroll
  for (int j = 0; j < 4; ++j) {
    int u = u0 + wn * 64 + j * 16 + m15;
#pragma unroll
    for (int i = 0; i < 4; ++i) {
      int rowb = outrow0 + wm * 64 + i * 16 + q4 * 4;
      int spb = s0loc + wm * 64 + i * 16 + q4 * 4;
#pragma unroll
      for (int r = 0; r < 4; ++r) {
        int sp = spb + r;
        bool selA = (u >= 1023 - sp);
        int mrow = selA ? sp : (sp > 0 ? sp - 1 : 0);
        int mcol = selA ? (u + sp - 1023) : (u + sp + 1025);
        float mval = b2f(maskb[mrow * 2048 + mcol]);
        Bh[(rowb + r) * 2048 + u] = f2b(acc[i][j][r] + mval);
      }
    }
  }
}

// ------- fused attention: superphase pipeline honoring in-order vmcnt -------
// wave = (st s-tile 16 rows, th T-half of 1024). Superphase = 2 chunks (64 t).
// Issue order per superphase: [V/K both chunks] -> [Bh batch for superphase+2]
// -> [work c0, work c1]. All waits inside a superphase target V/K that are
// OLDER than the Bh batch, so counted vmcnt leaves the batch in flight; it is
// drained one superphase later (~700cy old) -> Bh HBM latency mostly hidden.
// V is read from the transposed region inside kv (split-row mapping).
__global__ __launch_bounds__(256) void attn_kernel(
    const ushort* __restrict__ qb, const ushort* __restrict__ kv,
    const ushort* __restrict__ Bh, const ushort* __restrict__ maskb,
    ushort* __restrict__ attn) {
  __shared__ ushort Pp[4][16 * 36];
  __shared__ float comb[2][16][68];
  __shared__ float csum[32];

  const int tid = threadIdx.x;
  const int w = tid >> 6, lane = tid & 63, m15 = lane & 15, q4 = lane >> 4;
  const int st = w & 1, th = w >> 1;
  const int s0w = blockIdx.x * 32 + st * 16;
  const int h = blockIdx.y, b = blockIdx.z;
  const int s_l = q4 * 4;

  const ushort* qp = &qb[((b << 10) + s0w + m15) * 1024 + (h << 6) + q4 * 8];
  const short8 af0 = *(const short8*)qp;
  const short8 af1 = *(const short8*)(qp + 32);

  const ushort* kvb = &kv[((size_t)(b << 11) * 2048) + (h << 6)];
  const ushort* vrowb =
      &kv[((size_t)(((b << 10) + (h << 6)) << 1) + th) * 2048 + 1024];
  const int bhbase = ((b << 4) + h) << 21;   // *(1024*2048)
  ushort* pw = &Pp[w][0];

  int offA[4], offB[4], diagT[4];
  float dm[4];
#pragma unroll
  for (int i = 0; i < 4; ++i) {
    int s = s0w + s_l + i;
    offA[i] = bhbase + (s << 11) - s + 1023;
    offB[i] = bhbase + ((s + 1) << 11) - s - 1026;
    diagT[i] = s + 1025;
    dm[i] = (diagT[i] <= 2047) ? b2f(maskb[s * 2048 + diagT[i]]) : 0.f;
  }

  float lsum4[4] = {0.f, 0.f, 0.f, 0.f};
  float4v oacc[4] = {};

  auto pre_bh = [&](int t0, uint (&B)[4]) {
#pragma unroll
    for (int nt = 0; nt < 2; ++nt)
#pragma unroll
      for (int ip = 0; ip < 2; ++ip) {
        uint pk = 0;
#pragma unroll
        for (int k = 0; k < 2; ++k) {
          int i = ip * 2 + k;
          int t = t0 + nt * 16 + m15;
          int off = (t < diagT[i]) ? offA[i] : offB[i];
          ushort v = Bh[off + t];
          pk |= ((uint)v) << (16 * k);
        }
        B[nt * 2 + ip] = pk;
      }
  };

  auto loadKV = [&](int t0, short8 (&Kr)[2][2], short8 (&Vr)[4]) {
#pragma unroll
    for (int nt = 0; nt < 2; ++nt) {
      const ushort* kp = &kvb[(size_t)(t0 + nt * 16 + m15) * 2048 + q4 * 8];
      Kr[nt][0] = *(const short8*)kp;
      Kr[nt][1] = *(const short8*)(kp + 32);
    }
    int tc = (t0 & 1023) + q4 * 8;
#pragma unroll
    for (int nd = 0; nd < 4; ++nd)
      Vr[nd] = *(const short8*)(&vrowb[(size_t)(nd * 16 + m15) * 4096 + tc]);
  };

  auto work = [&](int t0, short8 (&Kr)[2][2], short8 (&Vr)[4], uint (&B)[4]) {
    float4v a0 = {}, a1 = {};
    a0 = __builtin_amdgcn_mfma_f32_16x16x32_bf16(af0, Kr[0][0], a0, 0, 0, 0);
    a0 = __builtin_amdgcn_mfma_f32_16x16x32_bf16(af1, Kr[0][1], a0, 0, 0, 0);
    a1 = __builtin_amdgcn_mfma_f32_16x16x32_bf16(af0, Kr[1][0], a1, 0, 0, 0);
    a1 = __builtin_amdgcn_mfma_f32_16x16x32_bf16(af1, Kr[1][1], a1, 0, 0, 0);
#pragma unroll
    for (int nt = 0; nt < 2; ++nt)
#pragma unroll
      for (int i = 0; i < 4; ++i) {
        int t = t0 + nt * 16 + m15;
        uint u = B[nt * 2 + (i >> 1)];
        uint bits = (i & 1) ? (u & 0xffff0000u) : (u << 16);
        float bv = (t == diagT[i]) ? dm[i] : __uint_as_float(bits);
        float a = (nt == 0) ? a0[i] : a1[i];
        float p = __expf(a + bv);
        lsum4[i] += p;
        pw[(s_l + i) * 36 + nt * 16 + m15] = f2b(p);
      }
    short8 pfr = *(const short8*)(&pw[m15 * 36 + q4 * 8]);
#pragma unroll
    for (int nd = 0; nd < 4; ++nd)
      oacc[nd] =
          __builtin_amdgcn_mfma_f32_16x16x32_bf16(pfr, Vr[nd], oacc[nd], 0, 0, 0);
  };

  const int tb = th * 1024;
  uint Bb0[4], Bb1[4], Bn0[4], Bn1[4];
  pre_bh(tb, Bb0);
  pre_bh(tb + 32, Bb1);
  pre_bh(tb + 64, Bn0);
  pre_bh(tb + 96, Bn1);
  for (int p = 0; p < 16; ++p) {
    const int t0 = tb + p * 64;
    short8 K0[2][2], V0[4], K1[2][2], V1[4];
    loadKV(t0, K0, V0);
    loadKV(t0 + 32, K1, V1);
    __builtin_amdgcn_sched_barrier(0);   // pin: V/K issued before Bh batch
    uint Bt0[4], Bt1[4];
    if (p < 14) {
      pre_bh(t0 + 128, Bt0);
      pre_bh(t0 + 160, Bt1);
    }
    __builtin_amdgcn_sched_barrier(0);   // pin: Bh batch before compute waits
    work(t0, K0, V0, Bb0);
    work(t0 + 32, K1, V1, Bb1);
#pragma unroll
    for (int j = 0; j < 4; ++j) {
      Bb0[j] = Bn0[j];
      Bb1[j] = Bn1[j];
    }
    if (p < 14) {
#pragma unroll
      for (int j = 0; j < 4; ++j) {
        Bn0[j] = Bt0[j];
        Bn1[j] = Bt1[j];
      }
    }
  }

  // row sums across the 16 t-lanes (m15 butterfly)
#pragma unroll
  for (int i = 0; i < 4; ++i) {
    float v = lsum4[i];
    v += __shfl_xor(v, 1, 64);
    v += __shfl_xor(v, 2, 64);
    v += __shfl_xor(v, 4, 64);
    v += __shfl_xor(v, 8, 64);
    lsum4[i] = v;
  }
  // combine T-halves
  if (th == 1) {
#pragma unroll
    for (int nd = 0; nd < 4; ++nd)
#pragma unroll
      for (int i = 0; i < 4; ++i)
        comb[st][s_l + i][nd * 16 + m15] = oacc[nd][i];
    if (m15 == 0)
#pragma unroll
      for (int i = 0; i < 4; ++i) csum[st * 16 + s_l + i] = lsum4[i];
  }
  __syncthreads();
  if (th == 0) {
#pragma unroll
    for (int i = 0; i < 4; ++i) lsum4[i] += csum[st * 16 + s_l + i];
#pragma unroll
    for (int nd = 0; nd < 4; ++nd)
#pragma unroll
      for (int i = 0; i < 4; ++i) {
        float v = oacc[nd][i] + comb[st][s_l + i][nd * 16 + m15];
        attn[((b << 10) + s0w + s_l + i) * 1024 + (h << 6) + nd * 16 + m15] =
            f2b(v / lsum4[i]);
      }
  }
}

// ---------------------------------------------------------------- launch ----
extern "C" void kernel_launch(void* const* d_in, const int* in_sizes, int n_in,
                              void* d_out, int out_size, void* d_ws,
                              size_t ws_size, hipStream_t stream) {
  const float* x = (const float*)d_in[0];
  const float* mem = (const float*)d_in[1];
  const float* mask = (const float*)d_in[2];
  const float* rel = (const float*)d_in[3];
  const float* Wq = (const float*)d_in[4];
  const float* bq = (const float*)d_in[5];
  const float* Wke = (const float*)d_in[6];
  const float* bke = (const float*)d_in[7];
  const float* Wkr = (const float*)d_in[8];
  const float* bkr = (const float*)d_in[9];
  const float* Wv = (const float*)d_in[10];
  const float* bv = (const float*)d_in[11];
  const float* Wo = (const float*)d_in[12];
  const float* bo = (const float*)d_in[13];
  float* out = (float*)d_out;

  ushort* ws = (ushort*)d_ws;
  ushort* xt = ws;                          // 4096x1024
  ushort* xbrel = xt + 4096 * 1024;         // [xb(2048); relb(2048)] x 1024
  ushort* WqT = xbrel + 4096 * 1024;
  ushort* WkeT = WqT + 1024 * 1024;
  ushort* WvT = WkeT + 1024 * 1024;         // must stay adjacent to WkeT
  ushort* WkrT = WvT + 1024 * 1024;
  ushort* WoT = WkrT + 1024 * 1024;
  ushort* kv = WoT + 1024 * 1024;           // [4096][2048]: K cols<1024, V^T region
  ushort* qr = kv + 4096 * 2048;            // [qbuf(2048); Qrb(2048)] x 1024
  ushort* attn = qr + 4096 * 1024;          // 2048x1024
  ushort* maskb = attn + 2048 * 1024;       // 1024x2048 bf16 pre-scaled
  ushort* Bh = maskb + 1024 * 2048;         // [b*16+h][1024 s][2048 u] bf16
  ushort* relb = xbrel + 2048 * 1024;
  ushort* Qrb = qr + 2048 * 1024;           // Qrel, pre-scaled by 1/8

  preproc_kernel<<<4096, 256, 0, stream>>>(x, mem, rel, mask, xt, xbrel, relb,
                                           maskb);
  transpose_cvt5_kernel<<<dim3(32, 32, 5), 256, 0, stream>>>(
      Wq, Wke, Wkr, Wv, Wo, WqT, WkeT, WkrT, WvT, WoT);

  gemm_fused_kernel<<<768, 256, 0, stream>>>(xt, xbrel, WkeT, WqT, WkrT, bke,
                                             bv, bq, bkr, kv, qr);

  bhat_kernel<<<dim3(16, 16, 16), 256, 0, stream>>>(qr, Qrb, maskb, Bh);

  attn_kernel<<<dim3(SEQ / 32, NH, BATCH), 256, 0, stream>>>(qr, kv, Bh, maskb,
                                                             attn);

  gemm64_kernel<1><<<dim3(32, 8), 256, 0, stream>>>(attn, WoT, bo, out, 2048,
                                                    1024, 1024);
}

// Round 7
// 364.312 us; speedup vs baseline: 1.0239x; 1.0223x over previous
//
#include <hip/hip_runtime.h>

typedef unsigned short ushort;
typedef unsigned int uint;
typedef __attribute__((ext_vector_type(8))) short short8;
typedef __attribute__((ext_vector_type(4))) float float4v;

#define D_MODEL 1024
#define NH 16
#define DH 64
#define BATCH 2
#define SEQ 1024
#define MEMLEN 1024
#define TOT 2048
#define BROW 2056              // Bh row stride: 2048 + 8 phase pad
#define PLN (1024 * BROW)      // Bh plane size (per b,h)

__device__ __forceinline__ float b2f(ushort u) {
  return __uint_as_float(((uint)u) << 16);
}
__device__ __forceinline__ ushort f2b(float f) {
  uint i = __float_as_uint(f);
  uint r = (i + 0x7fffu + ((i >> 16) & 1u)) >> 16;
  return (ushort)r;
}
__device__ __forceinline__ void gld16(const ushort* g, ushort* l) {
  __builtin_amdgcn_global_load_lds(
      (const __attribute__((address_space(1))) void*)g,
      (__attribute__((address_space(3))) void*)l, 16, 0, 0);
}

// ---------------- fused preprocessing: concat+cast, rel cast, mask cast -----
__global__ __launch_bounds__(256) void preproc_kernel(
    const float* __restrict__ x, const float* __restrict__ mem,
    const float* __restrict__ rel, const float* __restrict__ mask,
    ushort* __restrict__ xt, ushort* __restrict__ xb,
    ushort* __restrict__ relb, ushort* __restrict__ maskb) {
  const int bid = blockIdx.x;
  if (bid < 2048) {
    int idx = bid * 256 + threadIdx.x;
    int row = idx >> 7;
    int c8 = (idx & 127) << 3;
    int b = row >> 11;
    int i = row & 2047;
    const float* src = (i < MEMLEN) ? &mem[((b << 10) + i) * D_MODEL]
                                    : &x[((b << 10) + (i - MEMLEN)) * D_MODEL];
    float4 f0 = *(const float4*)(&src[c8]);
    float4 f1 = *(const float4*)(&src[c8 + 4]);
    ushort u[8] = {f2b(f0.x), f2b(f0.y), f2b(f0.z), f2b(f0.w),
                   f2b(f1.x), f2b(f1.y), f2b(f1.z), f2b(f1.w)};
    *(uint4*)(&xt[row * D_MODEL + c8]) = *(const uint4*)u;
    if (i >= MEMLEN)
      *(uint4*)(&xb[((b << 10) + (i - MEMLEN)) * D_MODEL + c8]) =
          *(const uint4*)u;
  } else if (bid < 3072) {
    int idx = (bid - 2048) * 256 + threadIdx.x;
    int base = idx << 3;
    float4 f0 = *(const float4*)(&rel[base]);
    float4 f1 = *(const float4*)(&rel[base + 4]);
    ushort u[8] = {f2b(f0.x), f2b(f0.y), f2b(f0.z), f2b(f0.w),
                   f2b(f1.x), f2b(f1.y), f2b(f1.z), f2b(f1.w)};
    *(uint4*)(&relb[base]) = *(const uint4*)u;
  } else {
    int idx = (bid - 3072) * 256 + threadIdx.x;
    int base = idx << 3;
    float4 f0 = *(const float4*)(&mask[base]);
    float4 f1 = *(const float4*)(&mask[base + 4]);
    ushort u[8] = {f2b(f0.x * -1e9f), f2b(f0.y * -1e9f), f2b(f0.z * -1e9f),
                   f2b(f0.w * -1e9f), f2b(f1.x * -1e9f), f2b(f1.y * -1e9f),
                   f2b(f1.z * -1e9f), f2b(f1.w * -1e9f)};
    *(uint4*)(&maskb[base]) = *(const uint4*)u;
  }
}

// --------------------------- 5x transpose + cast to bf16 (one launch) -------
__global__ __launch_bounds__(256) void transpose_cvt5_kernel(
    const float* __restrict__ W0, const float* __restrict__ W1,
    const float* __restrict__ W2, const float* __restrict__ W3,
    const float* __restrict__ W4, ushort* __restrict__ T0,
    ushort* __restrict__ T1, ushort* __restrict__ T2, ushort* __restrict__ T3,
    ushort* __restrict__ T4) {
  __shared__ ushort tle[32][33];
  const float* W;
  ushort* T;
  switch (blockIdx.z) {
    case 0: W = W0; T = T0; break;
    case 1: W = W1; T = T1; break;
    case 2: W = W2; T = T2; break;
    case 3: W = W3; T = T3; break;
    default: W = W4; T = T4; break;
  }
  const int bx = blockIdx.x * 32, by = blockIdx.y * 32;
  const int tx = threadIdx.x & 31, ty = threadIdx.x >> 5;
#pragma unroll
  for (int j = 0; j < 32; j += 8)
    tle[ty + j][tx] = f2b(W[(by + ty + j) * 1024 + bx + tx]);
  __syncthreads();
#pragma unroll
  for (int j = 0; j < 32; j += 8)
    T[(bx + ty + j) * 1024 + by + tx] = tle[tx][ty + j];
}

// --------------- fused projection GEMM: KV + q + qrel in one launch ---------
// seg0 (bid<512): K cols -> kv (scaled 0.125, bke); V cols -> written DIRECTLY
//   TRANSPOSED into kv's V-half via split-row mapping.
// seg1 (bid>=512): qr = xbrel @ (WqT | WkrT by row); qrel rows scaled 0.125.
__global__ __launch_bounds__(256) void gemm_fused_kernel(
    const ushort* __restrict__ xt, const ushort* __restrict__ xbrel,
    const ushort* __restrict__ WkeT, const ushort* __restrict__ WqT,
    const ushort* __restrict__ WkrT, const float* __restrict__ bke,
    const float* __restrict__ bv, const float* __restrict__ bq,
    const float* __restrict__ bkr, ushort* __restrict__ kv,
    ushort* __restrict__ qr) {
  __shared__ ushort As[128 * 32];
  __shared__ ushort Bs[128 * 32];
  const int bid = blockIdx.x;
  const bool seg0 = (bid < 512);
  const ushort* A;
  const ushort* BT;
  int m0, n0;
  if (seg0) {
    m0 = (bid & 31) * 128;
    n0 = (bid >> 5) * 128;
    A = xt;
    BT = WkeT;   // rows >=1024 fall through into adjacent WvT
  } else {
    int g = bid - 512;
    m0 = (g & 31) * 128;
    n0 = (g >> 5) * 128;
    A = xbrel;
    BT = (m0 < 2048) ? WqT : WkrT;
  }
  const int tid = threadIdx.x;
  const int w = tid >> 6, lane = tid & 63, m15 = lane & 15, q4 = lane >> 4;
  const int wm = w & 1, wn = w >> 1;
  float4v acc[4][4] = {};
  const int c0 = tid, c1 = tid + 256;
  const int r0 = c0 >> 2, u0 = (c0 & 3) * 8;
  const int r1 = c1 >> 2, u1 = (c1 & 3) * 8;

  for (int kk = 0; kk < 1024; kk += 32) {
    __syncthreads();
    gld16(&A[(m0 + r0) * 1024 + kk + u0], &As[c0 * 8]);
    gld16(&A[(m0 + r1) * 1024 + kk + u1], &As[c1 * 8]);
    gld16(&BT[(n0 + r0) * 1024 + kk + u0], &Bs[c0 * 8]);
    gld16(&BT[(n0 + r1) * 1024 + kk + u1], &Bs[c1 * 8]);
    __syncthreads();
    short8 af[4], bf[4];
#pragma unroll
    for (int i = 0; i < 4; ++i)
      af[i] = *(const short8*)(&As[(wm * 64 + i * 16 + m15) * 32 + q4 * 8]);
#pragma unroll
    for (int j = 0; j < 4; ++j)
      bf[j] = *(const short8*)(&Bs[(wn * 64 + j * 16 + m15) * 32 + q4 * 8]);
#pragma unroll
    for (int i = 0; i < 4; ++i)
#pragma unroll
      for (int j = 0; j < 4; ++j)
        acc[i][j] =
            __builtin_amdgcn_mfma_f32_16x16x32_bf16(af[i], bf[j], acc[i][j], 0, 0, 0);
  }
#pragma unroll
  for (int j = 0; j < 4; ++j) {
    int col = n0 + wn * 64 + j * 16 + m15;
    if (seg0) {
      if (col < 1024) {
        float bb = bke[col];
#pragma unroll
        for (int i = 0; i < 4; ++i) {
          int rowb = m0 + wm * 64 + i * 16 + q4 * 4;
#pragma unroll
          for (int r = 0; r < 4; ++r)
            kv[(rowb + r) * 2048 + col] = f2b((acc[i][j][r] + bb) * 0.125f);
        }
      } else {
        float bb = bv[col - 1024];
#pragma unroll
        for (int i = 0; i < 4; ++i) {
          int rowb = m0 + wm * 64 + i * 16 + q4 * 4;
          int dg = ((rowb >> 11) << 10) + (col - 1024);
          size_t prow = (size_t)(dg * 2 + ((rowb >> 10) & 1)) * 2048 + 1024 +
                        (rowb & 1023);
          uint lo = (uint)f2b(acc[i][j][0] + bb) |
                    ((uint)f2b(acc[i][j][1] + bb) << 16);
          uint hi = (uint)f2b(acc[i][j][2] + bb) |
                    ((uint)f2b(acc[i][j][3] + bb) << 16);
          *(uint2*)(&kv[prow]) = make_uint2(lo, hi);
        }
      }
    } else {
      float bb = (m0 < 2048) ? bq[col] : bkr[col];
      float sc = (m0 < 2048) ? 1.0f : 0.125f;
#pragma unroll
      for (int i = 0; i < 4; ++i) {
        int rowb = m0 + wm * 64 + i * 16 + q4 * 4;
#pragma unroll
        for (int r = 0; r < 4; ++r)
          qr[(rowb + r) * 1024 + col] = f2b((acc[i][j][r] + bb) * sc);
      }
    }
  }
}

// -------------------------------------- 64x128-tile GEMM (output proj) ------
template <int EPI>
__global__ __launch_bounds__(256) void gemm64_kernel(
    const ushort* __restrict__ A, const ushort* __restrict__ BT,
    const float* __restrict__ bias, void* __restrict__ Cout, int M, int N,
    int K) {
  __shared__ ushort As[64 * 32];
  __shared__ ushort Bs[128 * 32];
  const int m0 = blockIdx.x * 64, n0 = blockIdx.y * 128;
  const int tid = threadIdx.x;
  const int w = tid >> 6, lane = tid & 63, m15 = lane & 15, q4 = lane >> 4;
  float4v acc[4][2] = {};
  const int ra = tid >> 2, ua = (tid & 3) * 8;
  const int c0 = tid, c1 = tid + 256;
  const int rb0 = c0 >> 2, ub0 = (c0 & 3) * 8;
  const int rb1 = c1 >> 2, ub1 = (c1 & 3) * 8;

  for (int kk = 0; kk < K; kk += 32) {
    __syncthreads();
    gld16(&A[(m0 + ra) * K + kk + ua], &As[tid * 8]);
    gld16(&BT[(n0 + rb0) * K + kk + ub0], &Bs[c0 * 8]);
    gld16(&BT[(n0 + rb1) * K + kk + ub1], &Bs[c1 * 8]);
    __syncthreads();
    short8 bf[2];
#pragma unroll
    for (int j = 0; j < 2; ++j)
      bf[j] = *(const short8*)(&Bs[(w * 32 + j * 16 + m15) * 32 + q4 * 8]);
#pragma unroll
    for (int i = 0; i < 4; ++i) {
      short8 af = *(const short8*)(&As[(i * 16 + m15) * 32 + q4 * 8]);
#pragma unroll
      for (int j = 0; j < 2; ++j)
        acc[i][j] =
            __builtin_amdgcn_mfma_f32_16x16x32_bf16(af, bf[j], acc[i][j], 0, 0, 0);
    }
  }
#pragma unroll
  for (int j = 0; j < 2; ++j) {
    int col = n0 + w * 32 + j * 16 + m15;
    float bv = bias[col];
#pragma unroll
    for (int i = 0; i < 4; ++i) {
      int rowb = m0 + i * 16 + q4 * 4;
#pragma unroll
      for (int r = 0; r < 4; ++r) {
        float v = acc[i][j][r] + bv;
        if (EPI == 1)
          ((float*)Cout)[(rowb + r) * N + col] = v;
        else
          ((ushort*)Cout)[(rowb + r) * N + col] = f2b(v);
      }
    }
  }
}

// ----------------------- Bhat batched GEMM (phase-padded rows) --------------
// Bh[plane][sp][u] = q[sp].Qrel[u] (both pre-scaled so product has the 1/8).
// Row sp stored at byte phase (sp+1)&7 with stride BROW so that every
// 8-element t-segment of band A (u = t-sp+1023) AND band B (u = t-sp-1026,
// row sp+1) is 16B-aligned for the consumer's vector loads.
__global__ __launch_bounds__(256) void bhat_kernel(
    const ushort* __restrict__ q, const ushort* __restrict__ Qrb,
    ushort* __restrict__ Bh) {
  __shared__ ushort As[2 * 128 * 32];
  __shared__ ushort Bs[2 * 128 * 32];
  const int bs0 = blockIdx.x * 128, u0 = blockIdx.y * 128, h = blockIdx.z;
  const int tid = threadIdx.x;
  const int w = tid >> 6, lane = tid & 63, m15 = lane & 15, q4 = lane >> 4;
  const int wm = w & 1, wn = w >> 1;

#pragma unroll
  for (int c = 0; c < 4; ++c) {
    int unit = c * 256 + tid;               // flat LDS ushort = unit*8
    int row = (unit >> 2) & 127, kh = unit >> 9, cu = unit & 3;
    gld16(&q[(bs0 + row) * 1024 + (h << 6) + kh * 32 + cu * 8], &As[unit * 8]);
    gld16(&Qrb[(u0 + row) * 1024 + (h << 6) + kh * 32 + cu * 8], &Bs[unit * 8]);
  }
  __syncthreads();

  float4v acc[4][4] = {};
#pragma unroll
  for (int kh = 0; kh < 2; ++kh) {
    short8 af[4], bf[4];
#pragma unroll
    for (int i = 0; i < 4; ++i)
      af[i] = *(const short8*)(&As[kh * 4096 + (wm * 64 + i * 16 + m15) * 32 + q4 * 8]);
#pragma unroll
    for (int j = 0; j < 4; ++j)
      bf[j] = *(const short8*)(&Bs[kh * 4096 + (wn * 64 + j * 16 + m15) * 32 + q4 * 8]);
#pragma unroll
    for (int i = 0; i < 4; ++i)
#pragma unroll
      for (int j = 0; j < 4; ++j)
        acc[i][j] =
            __builtin_amdgcn_mfma_f32_16x16x32_bf16(af[i], bf[j], acc[i][j], 0, 0, 0);
  }
  const int b = bs0 >> 10;
  const int s0loc = bs0 & 1023;
  const int pbase = ((b << 4) + h) * PLN;
#pragma unroll
  for (int j = 0; j < 4; ++j) {
    int u = u0 + wn * 64 + j * 16 + m15;
#pragma unroll
    for (int i = 0; i < 4; ++i) {
      int spb = s0loc + wm * 64 + i * 16 + q4 * 4;
#pragma unroll
      for (int r = 0; r < 4; ++r) {
        int sp = spb + r;
        Bh[pbase + sp * BROW + ((sp + 1) & 7) + u] = f2b(acc[i][j][r]);
      }
    }
  }
}

// ------ fused attention: vectorized B-gather via wave-private LDS -----------
// wave = (st s-tile 16 rows, th T-half). Chunk = 32 t. Per chunk:
//   1 dwordx4 load covers the whole 16x32 B-hat tile (lanes = row x seg;
//   alignment guaranteed by Bh's per-row phase pad), 1 dwordx4 for mask.
//   Redistribute via wave-private LDS (linear write, 2-way-free read).
// The 1-2 chunks/wave whose segments straddle the band boundary take a
// wave-uniform scalar slow path. Issue order per chunk keeps B loads
// YOUNGER than the K wait -> ~2 chunks of flight before drain (~800cy).
__global__ __launch_bounds__(256) void attn_kernel(
    const ushort* __restrict__ qb, const ushort* __restrict__ kv,
    const ushort* __restrict__ Bh, const ushort* __restrict__ maskb,
    ushort* __restrict__ attn) {
  __shared__ ushort Bt[4][512];
  __shared__ ushort Mt[4][512];
  __shared__ ushort Pp[4][16 * 36];
  __shared__ float comb[2][16][68];
  __shared__ float csum[32];

  const int tid = threadIdx.x;
  const int w = tid >> 6, lane = tid & 63, m15 = lane & 15, q4 = lane >> 4;
  const int st = w & 1, th = w >> 1;
  const int s0w = blockIdx.x * 32 + st * 16;
  const int h = blockIdx.y, b = blockIdx.z;
  const int s_l = q4 * 4;

  const ushort* qp = &qb[((b << 10) + s0w + m15) * 1024 + (h << 6) + q4 * 8];
  const short8 af0 = *(const short8*)qp;
  const short8 af1 = *(const short8*)(qp + 32);

  const ushort* kvb = &kv[((size_t)(b << 11) * 2048) + (h << 6)];
  const ushort* vrowb =
      &kv[((size_t)(((b << 10) + (h << 6)) << 1) + th) * 2048 + 1024];
  const int bhbase = ((b << 4) + h) * PLN;
  ushort* pw = &Pp[w][0];
  ushort* btw = &Bt[w][0];
  ushort* mtw = &Mt[w][0];

  // vector-load lane geometry: lr = row (0..15), lc = 8-elem segment
  const int lr = lane >> 2, lc = (lane & 3) * 8;
  const int sA = s0w + lr;
  const int vOffA = bhbase + sA * BROW + ((sA + 1) & 7) - sA + 1023;
  const int vOffB = bhbase + (sA + 1) * BROW + ((sA + 2) & 7) - sA - 1026;
  const int vDiag = sA + 1025;
  const ushort* mrow = &maskb[sA * 2048];

  // per-consumer-element offsets (slow path)
  int offA[4], offB[4], diagT[4];
#pragma unroll
  for (int i = 0; i < 4; ++i) {
    int s = s0w + s_l + i;
    offA[i] = bhbase + s * BROW + ((s + 1) & 7) - s + 1023;
    offB[i] = bhbase + (s + 1) * BROW + ((s + 2) & 7) - s - 1026;
    diagT[i] = s + 1025;
  }

  float lsum4[4] = {0.f, 0.f, 0.f, 0.f};
  float4v oacc[4] = {};
  const int tb = th * 1024;

  auto vB = [&](int c) -> short8 {
    int t = tb + c * 32 + lc;
    int off = (t + 7 < vDiag) ? vOffA : vOffB;
    return *(const short8*)(&Bh[off + t]);
  };
  auto vM = [&](int c) -> short8 {
    return *(const short8*)(&mrow[tb + c * 32 + lc]);
  };
  auto ldK = [&](int c, short8 (&K)[2][2]) {
    int t0 = tb + c * 32;
#pragma unroll
    for (int nt = 0; nt < 2; ++nt) {
      const ushort* kp = &kvb[(size_t)(t0 + nt * 16 + m15) * 2048 + q4 * 8];
      K[nt][0] = *(const short8*)kp;
      K[nt][1] = *(const short8*)(kp + 32);
    }
  };

  auto chunk = [&](int c, short8& Bc, short8& Mc, short8 (&Kc)[2][2],
                   short8 (&Kn)[2][2]) {
    const int t0 = tb + c * 32;
    // 1. consume old vector buffers into wave-private LDS (vm-waits 2-4 old)
    *(short8*)(&btw[lane * 8]) = Bc;
    *(short8*)(&mtw[lane * 8]) = Mc;
    // 2. prefetch next K (dbuf) + this chunk's V
    short8 Vc[4];
    {
      int tc = c * 32 + q4 * 8;
#pragma unroll
      for (int nd = 0; nd < 4; ++nd)
        Vc[nd] = *(const short8*)(&vrowb[(size_t)(nd * 16 + m15) * 4096 + tc]);
    }
    if (c < 31) ldK(c + 1, Kn);
    // 3. reissue B (distance 4) / M (distance 2) — younger than K(c) wait
    Bc = vB(c + 4 <= 31 ? c + 4 : 31);
    Mc = vM(c + 2 <= 31 ? c + 2 : 31);
    // 4. QK on current K (waits K(c) issued last chunk; B/M stay in flight)
    float4v a0 = {}, a1 = {};
    a0 = __builtin_amdgcn_mfma_f32_16x16x32_bf16(af0, Kc[0][0], a0, 0, 0, 0);
    a0 = __builtin_amdgcn_mfma_f32_16x16x32_bf16(af1, Kc[0][1], a0, 0, 0, 0);
    a1 = __builtin_amdgcn_mfma_f32_16x16x32_bf16(af0, Kc[1][0], a1, 0, 0, 0);
    a1 = __builtin_amdgcn_mfma_f32_16x16x32_bf16(af1, Kc[1][1], a1, 0, 0, 0);
    // 5. softmax from LDS tiles (fast) or scalar gather (straddle chunks)
    const bool slow = (t0 + 31 >= s0w + 1025) && (t0 <= s0w + 1040);
    if (!slow) {
#pragma unroll
      for (int nt = 0; nt < 2; ++nt)
#pragma unroll
        for (int i = 0; i < 4; ++i) {
          int li = (s_l + i) * 32 + nt * 16 + m15;
          float a = (nt == 0) ? a0[i] : a1[i];
          float p = __expf(a + b2f(btw[li]) + b2f(mtw[li]));
          lsum4[i] += p;
          pw[(s_l + i) * 36 + nt * 16 + m15] = f2b(p);
        }
    } else {
#pragma unroll
      for (int nt = 0; nt < 2; ++nt)
#pragma unroll
        for (int i = 0; i < 4; ++i) {
          int t = t0 + nt * 16 + m15;
          int li = (s_l + i) * 32 + nt * 16 + m15;
          float bv = (t == diagT[i])
                         ? 0.f
                         : b2f(Bh[((t < diagT[i]) ? offA[i] : offB[i]) + t]);
          float a = (nt == 0) ? a0[i] : a1[i];
          float p = __expf(a + bv + b2f(mtw[li]));
          lsum4[i] += p;
          pw[(s_l + i) * 36 + nt * 16 + m15] = f2b(p);
        }
    }
    // 6. PV
    short8 pfr = *(const short8*)(&pw[m15 * 36 + q4 * 8]);
#pragma unroll
    for (int nd = 0; nd < 4; ++nd)
      oacc[nd] =
          __builtin_amdgcn_mfma_f32_16x16x32_bf16(pfr, Vc[nd], oacc[nd], 0, 0, 0);
  };

  // prologue
  short8 B0 = vB(0), B1 = vB(1), B2 = vB(2), B3 = vB(3);
  short8 M0 = vM(0), M1 = vM(1);
  short8 Ka[2][2], Kb[2][2];
  ldK(0, Ka);
  for (int j = 0; j < 8; ++j) {
    int c = j * 4;
    chunk(c, B0, M0, Ka, Kb);
    chunk(c + 1, B1, M1, Kb, Ka);
    chunk(c + 2, B2, M0, Ka, Kb);
    chunk(c + 3, B3, M1, Kb, Ka);
  }

  // row sums across the 16 t-lanes (m15 butterfly)
#pragma unroll
  for (int i = 0; i < 4; ++i) {
    float v = lsum4[i];
    v += __shfl_xor(v, 1, 64);
    v += __shfl_xor(v, 2, 64);
    v += __shfl_xor(v, 4, 64);
    v += __shfl_xor(v, 8, 64);
    lsum4[i] = v;
  }
  // combine T-halves
  if (th == 1) {
#pragma unroll
    for (int nd = 0; nd < 4; ++nd)
#pragma unroll
      for (int i = 0; i < 4; ++i)
        comb[st][s_l + i][nd * 16 + m15] = oacc[nd][i];
    if (m15 == 0)
#pragma unroll
      for (int i = 0; i < 4; ++i) csum[st * 16 + s_l + i] = lsum4[i];
  }
  __syncthreads();
  if (th == 0) {
#pragma unroll
    for (int i = 0; i < 4; ++i) lsum4[i] += csum[st * 16 + s_l + i];
#pragma unroll
    for (int nd = 0; nd < 4; ++nd)
#pragma unroll
      for (int i = 0; i < 4; ++i) {
        float v = oacc[nd][i] + comb[st][s_l + i][nd * 16 + m15];
        attn[((b << 10) + s0w + s_l + i) * 1024 + (h << 6) + nd * 16 + m15] =
            f2b(v / lsum4[i]);
      }
  }
}

// ---------------------------------------------------------------- launch ----
extern "C" void kernel_launch(void* const* d_in, const int* in_sizes, int n_in,
                              void* d_out, int out_size, void* d_ws,
                              size_t ws_size, hipStream_t stream) {
  const float* x = (const float*)d_in[0];
  const float* mem = (const float*)d_in[1];
  const float* mask = (const float*)d_in[2];
  const float* rel = (const float*)d_in[3];
  const float* Wq = (const float*)d_in[4];
  const float* bq = (const float*)d_in[5];
  const float* Wke = (const float*)d_in[6];
  const float* bke = (const float*)d_in[7];
  const float* Wkr = (const float*)d_in[8];
  const float* bkr = (const float*)d_in[9];
  const float* Wv = (const float*)d_in[10];
  const float* bv = (const float*)d_in[11];
  const float* Wo = (const float*)d_in[12];
  const float* bo = (const float*)d_in[13];
  float* out = (float*)d_out;

  ushort* ws = (ushort*)d_ws;
  ushort* xt = ws;                          // 4096x1024
  ushort* xbrel = xt + 4096 * 1024;         // [xb(2048); relb(2048)] x 1024
  ushort* WqT = xbrel + 4096 * 1024;
  ushort* WkeT = WqT + 1024 * 1024;
  ushort* WvT = WkeT + 1024 * 1024;         // must stay adjacent to WkeT
  ushort* WkrT = WvT + 1024 * 1024;
  ushort* WoT = WkrT + 1024 * 1024;
  ushort* kv = WoT + 1024 * 1024;           // [4096][2048]: K cols<1024, V^T region
  ushort* qr = kv + 4096 * 2048;            // [qbuf(2048); Qrb(2048)] x 1024
  ushort* attn = qr + 4096 * 1024;          // 2048x1024
  ushort* maskb = attn + 2048 * 1024;       // 1024x2048 bf16 pre-scaled
  ushort* Bh = maskb + 1024 * 2048;         // 32 planes x 1024 x BROW bf16
  ushort* relb = xbrel + 2048 * 1024;
  ushort* Qrb = qr + 2048 * 1024;           // Qrel, pre-scaled by 1/8

  preproc_kernel<<<4096, 256, 0, stream>>>(x, mem, rel, mask, xt, xbrel, relb,
                                           maskb);
  transpose_cvt5_kernel<<<dim3(32, 32, 5), 256, 0, stream>>>(
      Wq, Wke, Wkr, Wv, Wo, WqT, WkeT, WkrT, WvT, WoT);

  gemm_fused_kernel<<<768, 256, 0, stream>>>(xt, xbrel, WkeT, WqT, WkrT, bke,
                                             bv, bq, bkr, kv, qr);

  bhat_kernel<<<dim3(16, 16, 16), 256, 0, stream>>>(qr, Qrb, Bh);

  attn_kernel<<<dim3(SEQ / 32, NH, BATCH), 256, 0, stream>>>(qr, kv, Bh, maskb,
                                                             attn);

  gemm64_kernel<1><<<dim3(32, 8), 256, 0, stream>>>(attn, WoT, bo, out, 2048,
                                                    1024, 1024);
}